// Round 1
// baseline (222.405 us; speedup 1.0000x reference)
//
#include <hip/hip_runtime.h>
#include <hip/hip_bf16.h>
#include <math.h>

#define V   50000
#define DIM 128
#define BB  512
#define LQ  30
#define RD  200
#define KN  21

// ---------------- kernel 1: L2-normalize embedding table ----------------
__global__ __launch_bounds__(256) void knrm_norm(const float* __restrict__ emb,
                                                 float* __restrict__ nemb) {
    int row  = blockIdx.x * 4 + (threadIdx.x >> 6);
    int lane = threadIdx.x & 63;
    if (row >= V) return;
    const float2 v = *reinterpret_cast<const float2*>(emb + (size_t)row * DIM + lane * 2);
    float ss = v.x * v.x + v.y * v.y;
#pragma unroll
    for (int off = 32; off; off >>= 1) ss += __shfl_xor(ss, off);
    float inv = 1.0f / fmaxf(sqrtf(ss), 1e-12f);
    float2 o;
    o.x = v.x * inv;
    o.y = v.y * inv;
    *reinterpret_cast<float2*>(nemb + (size_t)row * DIM + lane * 2) = o;
}

// ---------------- kernel 2: per-(pair,b) KNRM score ----------------
// block = 256 threads, thread (ty,tx) = (tid>>4, tid&15)
// M tile: rows {ty, ty+16} (query, padded to 32), cols {tx+16j, j=0..3} per 64-wide doc tile
__global__ __launch_bounds__(256) void knrm_main(
    const float* __restrict__ nemb,
    const float* __restrict__ W,
    const int* __restrict__ q1, const int* __restrict__ d1,
    const int* __restrict__ q2, const int* __restrict__ d2,
    float* __restrict__ logits)
{
    __shared__ float Qs[32][132];   // stride 132: float4-aligned, low bank conflict
    __shared__ float Ds[64][132];
    __shared__ float pbuf[16];

    const int b    = blockIdx.x;
    const int pair = blockIdx.y;
    const int tid  = threadIdx.x;
    const int tx   = tid & 15;
    const int ty   = tid >> 4;

    const int* qind = (pair == 0 ? q1 : q2) + b * LQ;
    const int* dind = (pair == 0 ? d1 : d2) + b * RD;

    // stage normalized query vectors (rows 30,31 zeroed)
    for (int e = tid; e < 32 * 128; e += 256) {
        int l = e >> 7, col = e & 127;
        float v = 0.0f;
        if (l < LQ) v = nemb[(size_t)qind[l] * DIM + col];
        Qs[l][col] = v;
    }

    float ksum[2][KN];
#pragma unroll
    for (int i = 0; i < 2; ++i)
#pragma unroll
        for (int k = 0; k < KN; ++k) ksum[i][k] = 0.0f;

    for (int r0 = 0; r0 < 256; r0 += 64) {
        __syncthreads();
        // stage doc tile (invalid rows zeroed)
        for (int e = tid; e < 64 * 128; e += 256) {
            int j = e >> 7, col = e & 127;
            int r = r0 + j;
            float v = 0.0f;
            if (r < RD) v = nemb[(size_t)dind[r] * DIM + col];
            Ds[j][col] = v;
        }
        __syncthreads();

        // 2x4 register tile of M
        float m00 = 0, m01 = 0, m02 = 0, m03 = 0;
        float m10 = 0, m11 = 0, m12 = 0, m13 = 0;
        for (int d = 0; d < 128; d += 4) {
            float4 a0 = *reinterpret_cast<const float4*>(&Qs[ty][d]);
            float4 a1 = *reinterpret_cast<const float4*>(&Qs[ty + 16][d]);
            float4 b0 = *reinterpret_cast<const float4*>(&Ds[tx][d]);
            float4 b1 = *reinterpret_cast<const float4*>(&Ds[tx + 16][d]);
            float4 b2 = *reinterpret_cast<const float4*>(&Ds[tx + 32][d]);
            float4 b3 = *reinterpret_cast<const float4*>(&Ds[tx + 48][d]);
            m00 += a0.x*b0.x; m01 += a0.x*b1.x; m02 += a0.x*b2.x; m03 += a0.x*b3.x;
            m10 += a1.x*b0.x; m11 += a1.x*b1.x; m12 += a1.x*b2.x; m13 += a1.x*b3.x;
            m00 += a0.y*b0.y; m01 += a0.y*b1.y; m02 += a0.y*b2.y; m03 += a0.y*b3.y;
            m10 += a1.y*b0.y; m11 += a1.y*b1.y; m12 += a1.y*b2.y; m13 += a1.y*b3.y;
            m00 += a0.z*b0.z; m01 += a0.z*b1.z; m02 += a0.z*b2.z; m03 += a0.z*b3.z;
            m10 += a1.z*b0.z; m11 += a1.z*b1.z; m12 += a1.z*b2.z; m13 += a1.z*b3.z;
            m00 += a0.w*b0.w; m01 += a0.w*b1.w; m02 += a0.w*b2.w; m03 += a0.w*b3.w;
            m10 += a1.w*b0.w; m11 += a1.w*b1.w; m12 += a1.w*b2.w; m13 += a1.w*b3.w;
        }
        float m[2][4] = {{m00, m01, m02, m03}, {m10, m11, m12, m13}};

        // 21-Gaussian kernel bank, masked accumulate
#pragma unroll
        for (int i = 0; i < 2; ++i) {
            int row = ty + 16 * i;
#pragma unroll
            for (int j = 0; j < 4; ++j) {
                int col = r0 + tx + 16 * j;
                if (row < LQ && col < RD) {
                    float mv = m[i][j];
#pragma unroll
                    for (int k = 0; k < 20; ++k) {
                        float t = mv - (float)(-0.95 + 0.1 * k);
                        ksum[i][k] += __expf(t * t * -50.0f);       // sigma=0.1
                    }
                    float t = mv - 1.0f;
                    ksum[i][20] += __expf(t * t * -500000.0f);      // sigma=0.001
                }
            }
        }
    }

    // reduce over tx (lanes differing in bits 0..3 — intra-wave)
#pragma unroll
    for (int k = 0; k < KN; ++k) {
        float v0 = ksum[0][k], v1 = ksum[1][k];
#pragma unroll
        for (int off = 1; off < 16; off <<= 1) {
            v0 += __shfl_xor(v0, off);
            v1 += __shfl_xor(v1, off);
        }
        ksum[0][k] = v0; ksum[1][k] = v1;
    }

    if (tx == 0) {
        float part = 0.0f;
#pragma unroll
        for (int k = 0; k < KN; ++k) {
            part += W[k] * log1pf(ksum[0][k]);
            if (ty + 16 < LQ) part += W[k] * log1pf(ksum[1][k]);
        }
        pbuf[ty] = part;
    }
    __syncthreads();
    if (tid == 0) {
        float logit = 0.0f;
#pragma unroll
        for (int i = 0; i < 16; ++i) logit += pbuf[i];
        logits[pair * BB + b] = logit;   // bias b cancels in sigmoid(l1-l2)
    }
}

// ---------------- kernel 3: sigmoid of logit difference ----------------
__global__ void knrm_final(const float* __restrict__ logits, float* __restrict__ out) {
    int i = blockIdx.x * blockDim.x + threadIdx.x;
    if (i < BB) {
        float x = logits[i] - logits[BB + i];
        out[i] = 1.0f / (1.0f + expf(-x));
    }
}

extern "C" void kernel_launch(void* const* d_in, const int* in_sizes, int n_in,
                              void* d_out, int out_size, void* d_ws, size_t ws_size,
                              hipStream_t stream) {
    const float* emb = (const float*)d_in[0];
    const float* W   = (const float*)d_in[1];
    const int* q1    = (const int*)d_in[3];
    const int* dd1   = (const int*)d_in[4];
    const int* q2    = (const int*)d_in[5];
    const int* dd2   = (const int*)d_in[6];

    float* nemb   = (float*)d_ws;                    // 50000*128 floats = 25.6 MB
    float* logits = nemb + (size_t)V * DIM;          // 1024 floats

    knrm_norm<<<(V + 3) / 4, 256, 0, stream>>>(emb, nemb);
    dim3 grid(BB, 2);
    knrm_main<<<grid, 256, 0, stream>>>(nemb, W, q1, dd1, q2, dd2, logits);
    knrm_final<<<2, 256, 0, stream>>>(logits, (float*)d_out);
}

// Round 2
// 87.001 us; speedup vs baseline: 2.5563x; 2.5563x over previous
//
#include <hip/hip_runtime.h>
#include <math.h>

#define V   50000
#define DIM 128
#define BB  512
#define LQ  30
#define RD  200
#define KN  21

typedef unsigned short ushort_t;
typedef __attribute__((ext_vector_type(8))) short bf16x8;   // 8 bf16 = 4 VGPRs
typedef __attribute__((ext_vector_type(4))) float f32x4;

#if __has_builtin(__builtin_amdgcn_exp2f)
#define EXP2F(x) __builtin_amdgcn_exp2f(x)
#else
#define EXP2F(x) __expf((x) * 0.69314718f)
#endif

static __device__ __forceinline__ ushort_t f2bf(float x) {
    unsigned u = __builtin_bit_cast(unsigned, x);
    return (ushort_t)((u + 0x7FFFu + ((u >> 16) & 1u)) >> 16);   // RNE
}
static __device__ __forceinline__ float bf2f(ushort_t h) {
    unsigned u = ((unsigned)h) << 16;
    return __builtin_bit_cast(float, u);
}
static __device__ __forceinline__ bf16x8 as_frag(int4 v) {
    return __builtin_bit_cast(bf16x8, v);
}

// ------------- kernel 1: normalize + split into hi/lo bf16 -------------
__global__ __launch_bounds__(256) void knrm_norm(const float* __restrict__ emb,
                                                 ushort_t* __restrict__ nh,
                                                 ushort_t* __restrict__ nl) {
    int row  = blockIdx.x * 4 + (threadIdx.x >> 6);
    int lane = threadIdx.x & 63;
    if (row >= V) return;
    const float2 v = *reinterpret_cast<const float2*>(emb + (size_t)row * DIM + lane * 2);
    float ss = v.x * v.x + v.y * v.y;
#pragma unroll
    for (int off = 32; off; off >>= 1) ss += __shfl_xor(ss, off);
    float inv = 1.0f / fmaxf(sqrtf(ss), 1e-12f);
    float x0 = v.x * inv, x1 = v.y * inv;
    ushort_t h0 = f2bf(x0), h1 = f2bf(x1);
    ushort_t l0 = f2bf(x0 - bf2f(h0)), l1 = f2bf(x1 - bf2f(h1));
    ushort2 ho; ho.x = h0; ho.y = h1;
    ushort2 lo; lo.x = l0; lo.y = l1;
    *reinterpret_cast<ushort2*>(nh + (size_t)row * DIM + lane * 2) = ho;
    *reinterpret_cast<ushort2*>(nl + (size_t)row * DIM + lane * 2) = lo;
}

// ------------- kernel 2: MFMA split-bf16 KNRM score -------------
// block = 256 (4 waves). wave = (rt = row-tile of 16 q-rows, half = 32-col half
// of the 64-col doc stage). Lane: r = lane&15 (col / q-row in frags), g = lane>>4.
// LDS tiles XOR-swizzled on 16B slots: slot' = slot ^ (row & 15).
__global__ __launch_bounds__(256) void knrm_mfma(
    const ushort_t* __restrict__ nh, const ushort_t* __restrict__ nl,
    const float* __restrict__ W,
    const int* __restrict__ q1, const int* __restrict__ d1,
    const int* __restrict__ q2, const int* __restrict__ d2,
    float* __restrict__ logits)
{
    __shared__ int4 sQh[512], sQl[512];      // 32 rows x 16 slots
    __shared__ int4 sDh[1024], sDl[1024];    // 64 rows x 16 slots
    __shared__ float pbuf[32];

    const int b = blockIdx.x, pair = blockIdx.y;
    const int tid = threadIdx.x;
    const int* qind = (pair ? q2 : q1) + b * LQ;
    const int* dind = (pair ? d2 : d1) + b * RD;

    // ---- stage Q once (rows 30,31 zero) ----
    for (int e = tid; e < 512; e += 256) {
        int rho = e >> 4, c = e & 15;
        int4 vh = {0, 0, 0, 0}, vl = {0, 0, 0, 0};
        if (rho < LQ) {
            size_t base = (size_t)qind[rho] * DIM + c * 8;
            vh = *(const int4*)(nh + base);
            vl = *(const int4*)(nl + base);
        }
        int slot = rho * 16 + (c ^ (rho & 15));
        sQh[slot] = vh;
        sQl[slot] = vl;
    }

    const int lane = tid & 63, wave = tid >> 6;
    const int r = lane & 15, g = lane >> 4;
    const int rt = wave & 1, half = wave >> 1;

    float ksum[4][KN];
#pragma unroll
    for (int j = 0; j < 4; ++j)
#pragma unroll
        for (int k = 0; k < KN; ++k) ksum[j][k] = 0.0f;

    const int qbase  = (rt * 16 + r) * 16;
    const int dbase0 = (half * 32 + r) * 16;
    const int dbase1 = (half * 32 + 16 + r) * 16;

    for (int r0 = 0; r0 < 256; r0 += 64) {
        __syncthreads();   // also covers Q staging before first compute
        for (int e = tid; e < 1024; e += 256) {
            int rho = e >> 4, c = e & 15;
            int gr = r0 + rho;
            int4 vh = {0, 0, 0, 0}, vl = {0, 0, 0, 0};
            if (gr < RD) {
                size_t base = (size_t)dind[gr] * DIM + c * 8;
                vh = *(const int4*)(nh + base);
                vl = *(const int4*)(nl + base);
            }
            int slot = rho * 16 + (c ^ (rho & 15));
            sDh[slot] = vh;
            sDl[slot] = vl;
        }
        __syncthreads();

        // ---- M-tile via 3-split bf16 MFMA: M = Ah*Bh + Ah*Bl + Al*Bh ----
        f32x4 acc0 = {0.f, 0.f, 0.f, 0.f}, acc1 = {0.f, 0.f, 0.f, 0.f};
#pragma unroll
        for (int ks = 0; ks < 4; ++ks) {
            int sl = (4 * ks + g) ^ r;
            bf16x8 ah  = as_frag(sQh[qbase + sl]);
            bf16x8 al  = as_frag(sQl[qbase + sl]);
            bf16x8 bh0 = as_frag(sDh[dbase0 + sl]);
            bf16x8 bl0 = as_frag(sDl[dbase0 + sl]);
            acc0 = __builtin_amdgcn_mfma_f32_16x16x32_bf16(ah, bh0, acc0, 0, 0, 0);
            acc0 = __builtin_amdgcn_mfma_f32_16x16x32_bf16(ah, bl0, acc0, 0, 0, 0);
            acc0 = __builtin_amdgcn_mfma_f32_16x16x32_bf16(al, bh0, acc0, 0, 0, 0);
            bf16x8 bh1 = as_frag(sDh[dbase1 + sl]);
            bf16x8 bl1 = as_frag(sDl[dbase1 + sl]);
            acc1 = __builtin_amdgcn_mfma_f32_16x16x32_bf16(ah, bh1, acc1, 0, 0, 0);
            acc1 = __builtin_amdgcn_mfma_f32_16x16x32_bf16(ah, bl1, acc1, 0, 0, 0);
            acc1 = __builtin_amdgcn_mfma_f32_16x16x32_bf16(al, bh1, acc1, 0, 0, 0);
        }

        // ---- 21-Gaussian bank, incremental quadratic exponent in log2 ----
        // C/D layout: col = lane&15, row = (lane>>4)*4 + j  (m89/m91 verified)
#pragma unroll
        for (int ct = 0; ct < 2; ++ct) {
            int col = r0 + half * 32 + ct * 16 + r;
#pragma unroll
            for (int j = 0; j < 4; ++j) {
                int row = rt * 16 + g * 4 + j;
                float m = ct ? acc1[j] : acc0[j];
                // invalid (row,col): m=16 -> every kernel underflows to exact 0
                m = (row < LQ && col < RD) ? m : 16.0f;
                float t0 = m + 0.95f;
                float e0 = (-72.134752f * t0) * t0;               // -50*log2e*t0^2
                float de = fmaf(14.4269504f, t0, -0.72134752f);
#pragma unroll
                for (int k = 0; k < 20; ++k) {
                    ksum[j][k] += EXP2F(e0);
                    e0 += de;
                    de -= 1.4426950f;
                }
                float t = m - 1.0f;                                // exact kernel
                ksum[j][20] += EXP2F((-721347.52f * t) * t);
            }
        }
    }

    __syncthreads();              // all frag reads done; sDh reused below
    float* kred = (float*)sDh;    // [2 halves][32 rows][21]

    // reduce over the 16 col-lanes (r)
#pragma unroll
    for (int j = 0; j < 4; ++j)
#pragma unroll
        for (int k = 0; k < KN; ++k) {
            float v = ksum[j][k];
            v += __shfl_xor(v, 1);
            v += __shfl_xor(v, 2);
            v += __shfl_xor(v, 4);
            v += __shfl_xor(v, 8);
            ksum[j][k] = v;
        }
    if (r == 0) {
        int rowb = rt * 16 + g * 4;
#pragma unroll
        for (int j = 0; j < 4; ++j)
#pragma unroll
            for (int k = 0; k < KN; ++k)
                kred[(half * 32 + rowb + j) * KN + k] = ksum[j][k];
    }
    __syncthreads();

    if (tid < 32) {
        float part = 0.0f;
        if (tid < LQ) {
#pragma unroll
            for (int k = 0; k < KN; ++k) {
                float s = kred[tid * KN + k] + kred[(32 + tid) * KN + k];
                part += W[k] * log1pf(s);
            }
        }
        pbuf[tid] = part;
    }
    __syncthreads();
    if (tid == 0) {
        float logit = 0.0f;
#pragma unroll
        for (int i = 0; i < LQ; ++i) logit += pbuf[i];
        logits[pair * BB + b] = logit;   // bias cancels in sigmoid(l1-l2)
    }
}

// ------------- kernel 3: sigmoid of logit difference -------------
__global__ void knrm_final(const float* __restrict__ logits, float* __restrict__ out) {
    int i = blockIdx.x * blockDim.x + threadIdx.x;
    if (i < BB) {
        float x = logits[i] - logits[BB + i];
        out[i] = 1.0f / (1.0f + expf(-x));
    }
}

extern "C" void kernel_launch(void* const* d_in, const int* in_sizes, int n_in,
                              void* d_out, int out_size, void* d_ws, size_t ws_size,
                              hipStream_t stream) {
    const float* emb = (const float*)d_in[0];
    const float* W   = (const float*)d_in[1];
    const int* q1    = (const int*)d_in[3];
    const int* dd1   = (const int*)d_in[4];
    const int* q2    = (const int*)d_in[5];
    const int* dd2   = (const int*)d_in[6];

    ushort_t* nh  = (ushort_t*)d_ws;                 // V*128 bf16 hi = 12.8 MB
    ushort_t* nl  = nh + (size_t)V * DIM;            // V*128 bf16 lo = 12.8 MB
    float* logits = (float*)(nl + (size_t)V * DIM);  // 1024 floats

    knrm_norm<<<(V + 3) / 4, 256, 0, stream>>>(emb, nh, nl);
    dim3 grid(BB, 2);
    knrm_mfma<<<grid, 256, 0, stream>>>(nh, nl, W, q1, dd1, q2, dd2, logits);
    knrm_final<<<2, 256, 0, stream>>>(logits, (float*)d_out);
}